// Round 2
// baseline (1383.013 us; speedup 1.0000x reference)
//
#include <hip/hip_runtime.h>
#include <stdint.h>

// FusedGPTQMLP on MI355X (gfx950).
// Round 8: register-double-buffered fragment reads (read-ahead by one phase)
// so the LDS pipe drains DURING the MFMA epoch instead of alternating with it.
// One barrier per phase, counted vmcnt(2) waits, setprio around MFMA.
// 256x256 tile, BK=64, 8 waves, 128 KiB LDS double buffer.
// ws: xb [M,HIDDEN] bf16 | gi [MC,INTER] bf16 | wb weight chunk (adaptive).

#define HIDDEN 4096
#define INTER  11008
#define BM 256
#define BN 256
#define BK 64

typedef __bf16 bf16x8 __attribute__((ext_vector_type(8)));
typedef float f32x4 __attribute__((ext_vector_type(4)));

__device__ __forceinline__ ushort f2bf_rne(float f) {
  uint32_t u = __float_as_uint(f);
  u += 0x7FFFu + ((u >> 16) & 1u);
  return (ushort)(u >> 16);
}

__device__ __forceinline__ float bf2f(ushort h) {
  return __uint_as_float(((uint32_t)h) << 16);
}

// fp32 -> bf16 bulk convert, 4 elements/thread.
__global__ void f32_to_bf16_kernel(const float* __restrict__ src,
                                   ushort* __restrict__ dst, int n4) {
  const int i = blockIdx.x * 256 + threadIdx.x;
  if (i < n4) {
    const float4 v = ((const float4*)src)[i];
    ushort4 o;
    o.x = f2bf_rne(v.x); o.y = f2bf_rne(v.y);
    o.z = f2bf_rne(v.z); o.w = f2bf_rne(v.w);
    ((ushort4*)dst)[i] = o;
  }
}

// Dequant qweight[k8][n] (8 k-nibbles per int32) into packet layout:
// Bp[(k8*nc + n_local)*8 + j] = W[k8*8+j][n0+n_local], bf16. Scales fp32.
__global__ void dequant_kernel(const int32_t* __restrict__ qw,
                               const float* __restrict__ sc,
                               const int32_t* __restrict__ zr,
                               ushort* __restrict__ Bp,
                               int Nfull, int n0, int nc) {
  const int n_local = blockIdx.x * 128 + threadIdx.x;
  const int k8 = blockIdx.y;
  const int n = n0 + n_local;
  const int g = k8 >> 4;  // groupsize 128 => 16 k8-rows per group
  const uint32_t q = (uint32_t)qw[(size_t)k8 * Nfull + n];
  const float s = sc[(size_t)g * Nfull + n];
  const uint32_t zv = (uint32_t)zr[(size_t)g * (Nfull >> 3) + (n >> 3)];
  const int z1 = (int)((zv >> ((n & 7) * 4)) & 15u) + 1;
  union { ushort h[8]; uint4 v; } o;
#pragma unroll
  for (int j = 0; j < 8; j++) {
    const int qi = (int)((q >> (4 * j)) & 15u) - z1;  // (q - (z+1)), exact int
    o.h[j] = f2bf_rne((float)qi * s);
  }
  *(uint4*)(Bp + ((size_t)k8 * nc + n_local) * 8) = o.v;
}

#define GL_LDS(gp, lp)                                                        \
  __builtin_amdgcn_global_load_lds(                                           \
      (const __attribute__((address_space(1))) uint32_t*)(gp),                \
      (__attribute__((address_space(3))) uint32_t*)(lp), 16, 0, 0)
#define BAR()  do { __builtin_amdgcn_s_barrier(); asm volatile("" ::: "memory"); } while (0)
#define WVM4() asm volatile("s_waitcnt vmcnt(4)" ::: "memory")
#define WVM2() asm volatile("s_waitcnt vmcnt(2)" ::: "memory")
#define WVM0() asm volatile("s_waitcnt vmcnt(0)" ::: "memory")
#define WLG0() asm volatile("s_waitcnt lgkmcnt(0)" ::: "memory")
#define SCHED0() __builtin_amdgcn_sched_barrier(0)

// C[m, n] = A[m, :] @ W[:, n] over this chunk's nc columns.
// A: bf16 [rows, lda] (pre-offset). Bp: packets [K/8][nc][8] bf16.
// MODE 0: C bf16 = result. MODE 1: C bf16 = silu(C_old) * result (SwiGLU).
// MODE 2: C fp32 = result (final output).
//
// Schedule per K-tile (4 phases; MFMA fragment set alternates so the
// ds_reads issued in phase k feed phase k+1's MFMA — LDS delivery overlaps
// the MFMA epoch):
//  PH1: [vmcnt2][BAR][lgkm0] read afs1<-A1kk0 | stage A0' | MFMA afs0*bfs0 -> acc[0..3]
//  PH2: [vmcnt2][BAR][lgkm0] read afs0<-A0kk1, bfs1<-Bkk1 | stage B0' | MFMA afs1*bfs0 -> acc[4..7]
//  PH3: [     ][BAR][lgkm0] read afs1<-A1kk1 | stage A1' | MFMA afs0*bfs1 -> acc[0..3]
//  PH4: [vmcnt2][BAR][lgkm0] read afs0<-A0'kk0, bfs0<-B0'kk0 (next buf) | stage B1' | MFMA afs1*bfs1 -> acc[4..7]
template <int MODE>
__launch_bounds__(512, 2)
__global__ void gemm_bt_kernel(const ushort* __restrict__ A,
                               const ushort* __restrict__ Bp,
                               void* __restrict__ Cv,
                               int K, int nc, int lda, int ldc) {
  __shared__ ushort sAs[2][BM * BK];           // 2 x 32 KB
  __shared__ ushort sBs[2][(BK / 8) * BN * 8]; // 2 x 32 KB

  const int tid = threadIdx.x;
  const int w = tid >> 6;
  const int lane = tid & 63;
  const int l16 = lane & 15;
  const int quad = lane >> 4;
  const int wm16 = (w >> 2) * 16;   // 2 waves along M
  const int wn = (w & 3) * 64;      // 4 waves along N
  const int swz = l16 & 7;          // A-tile XOR swizzle key (row & 7)

  // Bijective XCD-aware block swizzle (m204 form).
  const int gx = gridDim.x;
  const int nwg = gx * (int)gridDim.y;
  const int orig = blockIdx.y * gx + blockIdx.x;
  const int q8 = nwg >> 3, r8 = nwg & 7;
  const int xcd = orig & 7, sidx = orig >> 3;
  const int wg = (xcd < r8 ? xcd * (q8 + 1) : r8 * (q8 + 1) + (xcd - r8) * q8) + sidx;
  const int m0 = (wg / gx) * BM;
  const int bn0 = (wg % gx) * BN;

  // Staging lane geometry.
  const int arow = tid >> 3;                      // 0..63 within 64-row slab
  const int apk8 = ((tid & 7) ^ (arow & 7)) * 8;  // swizzled source packet
  const int bpr = tid >> 8;                       // 0..1 packet-row in slab
  const int bcol = tid & 255;
  const ushort* aSrc = A + (size_t)(m0 + arow) * lda + apk8;
  const ushort* bSrc = Bp + ((size_t)bpr * nc + bn0 + bcol) * 8;

  f32x4 acc[8][4];
#pragma unroll
  for (int a = 0; a < 8; a++)
#pragma unroll
    for (int j = 0; j < 4; j++) acc[a][j] = (f32x4){0.f, 0.f, 0.f, 0.f};

  bf16x8 afs0[4], afs1[4], bfs0[4], bfs1[4];

  const int NT = K / BK;

#define STAGE_A(r, buf, kt) \
  GL_LDS(aSrc + (size_t)(r) * 64 * lda + (kt), (buf) + (r) * 4096 + w * 512)
#define STAGE_B(r, buf, kp) \
  GL_LDS(bSrc + ((kp) + (size_t)(r) * 2) * (size_t)nc * 8, (buf) + (r) * 4096 + w * 512)
  // LDS read bases (element offsets, ushorts):
  //   A row r, k-packet p: r*64 + ((p ^ (r&7)) * 8)   (rows here have r&7 == l16&7)
  //   B packet p, col n:   (p*256 + n) * 8

  // Prologue: stage tile 0 (order A0,B0,A1,B1); wait A0,B0; pre-issue PH1 reads.
  {
    ushort* sA0 = sAs[0];
    ushort* sB0 = sBs[0];
    STAGE_A(0, sA0, (size_t)0); STAGE_A(1, sA0, (size_t)0);  // A rows 0-127
    STAGE_B(0, sB0, (size_t)0); STAGE_B(1, sB0, (size_t)0);  // B packets 0-3
    STAGE_A(2, sA0, (size_t)0); STAGE_A(3, sA0, (size_t)0);  // A rows 128-255
    STAGE_B(2, sB0, (size_t)0); STAGE_B(3, sB0, (size_t)0);  // B packets 4-7
    WVM4();  // A0,B0 landed (A1,B1 still in flight)
    BAR();
    const ushort* a0 = sA0 + (size_t)(wm16 + l16) * 64;
#pragma unroll
    for (int i = 0; i < 4; i++)
      afs0[i] = *(const bf16x8*)(a0 + i * 2048 + ((quad ^ swz) * 8));
#pragma unroll
    for (int j = 0; j < 4; j++)
      bfs0[j] = *(const bf16x8*)(sB0 + ((size_t)(quad * 256) + wn + j * 16 + l16) * 8);
  }

#pragma unroll 1
  for (int t = 0; t < NT; ++t) {
    const ushort* sAc = sAs[t & 1];
    const ushort* sBc = sBs[t & 1];
    ushort* sAn = sAs[(t & 1) ^ 1];
    ushort* sBn = sBs[(t & 1) ^ 1];
    const int tn = (t + 1 < NT) ? t + 1 : t;  // clamp: re-stage last tile
    const size_t ktn = (size_t)tn * BK;
    const size_t kpn = (size_t)tn * 8;
    const ushort* aLo = sAc + (size_t)(wm16 + l16) * 64;        // rows 0-127 base
    const ushort* aHi = aLo + 128 * 64;                          // rows 128-255

    // ---- PH1 ----
    WVM2();  // tile-t A1 landed (needed by this phase's reads)
    BAR(); WLG0(); SCHED0();
#pragma unroll
    for (int i = 0; i < 4; i++)
      afs1[i] = *(const bf16x8*)(aHi + i * 2048 + ((quad ^ swz) * 8));
    STAGE_A(0, sAn, ktn); STAGE_A(1, sAn, ktn);
    SCHED0();
    __builtin_amdgcn_s_setprio(1);
#pragma unroll
    for (int i = 0; i < 4; i++)
#pragma unroll
      for (int j = 0; j < 4; j++)
        acc[i][j] = __builtin_amdgcn_mfma_f32_16x16x32_bf16(afs0[i], bfs0[j], acc[i][j], 0, 0, 0);
    __builtin_amdgcn_s_setprio(0);

    // ---- PH2 ----
    WVM2();  // tile-t B1 landed
    BAR(); WLG0(); SCHED0();
#pragma unroll
    for (int i = 0; i < 4; i++)
      afs0[i] = *(const bf16x8*)(aLo + i * 2048 + (((4 ^ quad) ^ swz) * 8));
#pragma unroll
    for (int j = 0; j < 4; j++)
      bfs1[j] = *(const bf16x8*)(sBc + ((size_t)((4 + quad) * 256) + wn + j * 16 + l16) * 8);
    STAGE_B(0, sBn, kpn); STAGE_B(1, sBn, kpn);
    SCHED0();
    __builtin_amdgcn_s_setprio(1);
#pragma unroll
    for (int i = 0; i < 4; i++)
#pragma unroll
      for (int j = 0; j < 4; j++)
        acc[4 + i][j] = __builtin_amdgcn_mfma_f32_16x16x32_bf16(afs1[i], bfs0[j], acc[4 + i][j], 0, 0, 0);
    __builtin_amdgcn_s_setprio(0);

    // ---- PH3 ---- (no vmcnt: reads only long-landed data)
    BAR(); WLG0(); SCHED0();
#pragma unroll
    for (int i = 0; i < 4; i++)
      afs1[i] = *(const bf16x8*)(aHi + i * 2048 + (((4 ^ quad) ^ swz) * 8));
    STAGE_A(2, sAn, ktn); STAGE_A(3, sAn, ktn);
    SCHED0();
    __builtin_amdgcn_s_setprio(1);
#pragma unroll
    for (int i = 0; i < 4; i++)
#pragma unroll
      for (int j = 0; j < 4; j++)
        acc[i][j] = __builtin_amdgcn_mfma_f32_16x16x32_bf16(afs0[i], bfs1[j], acc[i][j], 0, 0, 0);
    __builtin_amdgcn_s_setprio(0);

    // ---- PH4 ---- (reads next tile's A0/B0 from the other buffer)
    WVM2();  // next-tile A0,B0 landed (leaves next A1 in flight)
    BAR(); WLG0(); SCHED0();
    {
      const ushort* aNx = sAn + (size_t)(wm16 + l16) * 64;
#pragma unroll
      for (int i = 0; i < 4; i++)
        afs0[i] = *(const bf16x8*)(aNx + i * 2048 + ((quad ^ swz) * 8));
#pragma unroll
      for (int j = 0; j < 4; j++)
        bfs0[j] = *(const bf16x8*)(sBn + ((size_t)(quad * 256) + wn + j * 16 + l16) * 8);
    }
    STAGE_B(2, sBn, kpn); STAGE_B(3, sBn, kpn);
    SCHED0();
    __builtin_amdgcn_s_setprio(1);
#pragma unroll
    for (int i = 0; i < 4; i++)
#pragma unroll
      for (int j = 0; j < 4; j++)
        acc[4 + i][j] = __builtin_amdgcn_mfma_f32_16x16x32_bf16(afs1[i], bfs1[j], acc[4 + i][j], 0, 0, 0);
    __builtin_amdgcn_s_setprio(0);
  }
  WVM0();  // drain trailing (re-)staged loads before epilogue

  // Epilogue. C/D layout: col = lane&15, row = quad*4 + reg.
  // Row mapping: gm = m0 + (a>>2)*128 + (a&3)*32 + wm16 + quad*4 + r.
#pragma unroll
  for (int a = 0; a < 8; a++) {
    const int gmb = m0 + (a >> 2) * 128 + (a & 3) * 32 + wm16 + quad * 4;
#pragma unroll
    for (int r = 0; r < 4; r++) {
      const int gm = gmb + r;
      if (MODE == 2) {
        float* crow = (float*)Cv + (size_t)gm * ldc + bn0 + wn;
#pragma unroll
        for (int j = 0; j < 4; j++) crow[j * 16 + l16] = acc[a][j][r];
      } else {
        ushort* crow = (ushort*)Cv + (size_t)gm * ldc + bn0 + wn;
#pragma unroll
        for (int j = 0; j < 4; j++) {
          float v = acc[a][j][r];
          if (MODE == 1) {
            const float gv = bf2f(crow[j * 16 + l16]);     // gate (bf16)
            v = (gv / (1.0f + __expf(-gv))) * v;           // silu(gate) * up
          }
          crow[j * 16 + l16] = f2bf_rne(v);
        }
      }
    }
  }
}

extern "C" void kernel_launch(void* const* d_in, const int* in_sizes, int n_in,
                              void* d_out, int out_size, void* d_ws, size_t ws_size,
                              hipStream_t stream) {
  (void)n_in; (void)out_size;
  const float*   x   = (const float*)d_in[0];    // fp32 [4096, 4096]
  const int32_t* gq  = (const int32_t*)d_in[1];  // [512, 11008]
  const float*   gs  = (const float*)d_in[2];    // fp32 [32, 11008]
  const int32_t* gz  = (const int32_t*)d_in[3];  // [32, 1376]
  const int32_t* uq  = (const int32_t*)d_in[4];
  const float*   us  = (const float*)d_in[5];
  const int32_t* uz  = (const int32_t*)d_in[6];
  const int32_t* dq  = (const int32_t*)d_in[7];  // [1376, 4096]
  const float*   dsc = (const float*)d_in[8];    // fp32 [86, 4096]
  const int32_t* dz  = (const int32_t*)d_in[9];  // [86, 512]
  float* outp = (float*)d_out;                   // fp32 [4096, 4096]

  const int M = in_sizes[0] / HIDDEN;            // 4096

  // ---- ws-size-adaptive plan (all scratch strictly inside d_ws) ----
  const size_t W = ws_size;
  const size_t col12 = (size_t)HIDDEN * 2;   // 8192 B per dequant col (K=HIDDEN)
  const size_t col3  = (size_t)INTER * 2;    // 22016 B per dequant col (K=INTER)
  const size_t xb_bytes = (size_t)M * HIDDEN * 2;   // 33.5 MB
  int MC = 256;
  for (int cand = M; cand >= 256; cand >>= 1) {
    if (xb_bytes + (size_t)cand * INTER * 2 + col3 * 256 <= W) { MC = cand; break; }
  }
  ushort* xb = (ushort*)d_ws;                              // [M, HIDDEN] bf16
  ushort* gi = xb + (size_t)M * HIDDEN;                    // [MC, INTER] bf16
  ushort* wb = gi + (size_t)MC * INTER;                    // weight chunk
  const size_t used = xb_bytes + (size_t)MC * INTER * 2;
  const size_t wbuf = (W > used) ? W - used : 0;
  int NC12 = (int)(wbuf / col12); NC12 &= ~255;
  if (NC12 < 256) NC12 = 256;
  if (NC12 > INTER) NC12 = INTER;            // 11008 = 43*256
  int NC3 = (int)(wbuf / col3); NC3 &= ~255;
  if (NC3 < 256) NC3 = 256;
  if (NC3 > HIDDEN) NC3 = HIDDEN;

  // Convert x (fp32) -> xb (bf16) once.
  const int n4 = M * HIDDEN / 4;
  f32_to_bf16_kernel<<<(n4 + 255) / 256, 256, 0, stream>>>(x, xb, n4);

  for (int m0 = 0; m0 < M; m0 += MC) {
    const ushort* xm = xb + (size_t)m0 * HIDDEN;
    // Phase 1: gate = x @ Wg   (into gi, bf16)
    for (int n0 = 0; n0 < INTER; ) {
      int nc = INTER - n0; if (nc > NC12) nc = NC12;
      dequant_kernel<<<dim3(nc / 128, HIDDEN / 8), 128, 0, stream>>>(
          gq, gs, gz, wb, INTER, n0, nc);
      gemm_bt_kernel<0><<<dim3(nc / BN, MC / BM), 512, 0, stream>>>(
          xm, wb, gi + n0, HIDDEN, nc, HIDDEN, INTER);
      n0 += nc;
    }
    // Phase 2: inter = silu(gate) * (x @ Wu)   (in place over gi)
    for (int n0 = 0; n0 < INTER; ) {
      int nc = INTER - n0; if (nc > NC12) nc = NC12;
      dequant_kernel<<<dim3(nc / 128, HIDDEN / 8), 128, 0, stream>>>(
          uq, us, uz, wb, INTER, n0, nc);
      gemm_bt_kernel<1><<<dim3(nc / BN, MC / BM), 512, 0, stream>>>(
          xm, wb, gi + n0, HIDDEN, nc, HIDDEN, INTER);
      n0 += nc;
    }
    // Phase 3: out = inter @ Wd   (fp32 out)
    for (int n0 = 0; n0 < HIDDEN; ) {
      int nc = HIDDEN - n0; if (nc > NC3) nc = NC3;
      dequant_kernel<<<dim3(nc / 128, INTER / 8), 128, 0, stream>>>(
          dq, dsc, dz, wb, HIDDEN, n0, nc);
      gemm_bt_kernel<2><<<dim3(nc / BN, MC / BM), 512, 0, stream>>>(
          gi, wb, (void*)(outp + (size_t)m0 * HIDDEN + n0), INTER, nc, INTER, HIDDEN);
      n0 += nc;
    }
  }
}

// Round 3
// 1372.919 us; speedup vs baseline: 1.0074x; 1.0074x over previous
//
#include <hip/hip_runtime.h>
#include <stdint.h>

// FusedGPTQMLP on MI355X (gfx950).
// Round 9: faithful m201-style 8-phase / 2-K-step schedule. Stages land
// 5-7 phases before consumption; vmcnt(6) at phases 4 and 8 only (waits for
// loads issued >=3 phases earlier => free). Buffers parity-fixed (X=even
// step, Y=odd step). Fragment lgkm waits left to the compiler.
// 256x256 tile, BK=64, 8 waves (2M x 4N), 128 KiB LDS.
// ws: xb [M,HIDDEN] bf16 | gi [MC,INTER] bf16 | wb weight chunk (adaptive).

#define HIDDEN 4096
#define INTER  11008
#define BM 256
#define BN 256
#define BK 64

typedef __bf16 bf16x8 __attribute__((ext_vector_type(8)));
typedef float f32x4 __attribute__((ext_vector_type(4)));

__device__ __forceinline__ ushort f2bf_rne(float f) {
  uint32_t u = __float_as_uint(f);
  u += 0x7FFFu + ((u >> 16) & 1u);
  return (ushort)(u >> 16);
}

__device__ __forceinline__ float bf2f(ushort h) {
  return __uint_as_float(((uint32_t)h) << 16);
}

// fp32 -> bf16 bulk convert, 4 elements/thread.
__global__ void f32_to_bf16_kernel(const float* __restrict__ src,
                                   ushort* __restrict__ dst, int n4) {
  const int i = blockIdx.x * 256 + threadIdx.x;
  if (i < n4) {
    const float4 v = ((const float4*)src)[i];
    ushort4 o;
    o.x = f2bf_rne(v.x); o.y = f2bf_rne(v.y);
    o.z = f2bf_rne(v.z); o.w = f2bf_rne(v.w);
    ((ushort4*)dst)[i] = o;
  }
}

// Dequant qweight[k8][n] (8 k-nibbles per int32) into packet layout:
// Bp[(k8*nc + n_local)*8 + j] = W[k8*8+j][n0+n_local], bf16. Scales fp32.
__global__ void dequant_kernel(const int32_t* __restrict__ qw,
                               const float* __restrict__ sc,
                               const int32_t* __restrict__ zr,
                               ushort* __restrict__ Bp,
                               int Nfull, int n0, int nc) {
  const int n_local = blockIdx.x * 128 + threadIdx.x;
  const int k8 = blockIdx.y;
  const int n = n0 + n_local;
  const int g = k8 >> 4;  // groupsize 128 => 16 k8-rows per group
  const uint32_t q = (uint32_t)qw[(size_t)k8 * Nfull + n];
  const float s = sc[(size_t)g * Nfull + n];
  const uint32_t zv = (uint32_t)zr[(size_t)g * (Nfull >> 3) + (n >> 3)];
  const int z1 = (int)((zv >> ((n & 7) * 4)) & 15u) + 1;
  union { ushort h[8]; uint4 v; } o;
#pragma unroll
  for (int j = 0; j < 8; j++) {
    const int qi = (int)((q >> (4 * j)) & 15u) - z1;  // (q - (z+1)), exact int
    o.h[j] = f2bf_rne((float)qi * s);
  }
  *(uint4*)(Bp + ((size_t)k8 * nc + n_local) * 8) = o.v;
}

#define GL_LDS(gp, lp)                                                        \
  __builtin_amdgcn_global_load_lds(                                           \
      (const __attribute__((address_space(1))) uint32_t*)(gp),                \
      (__attribute__((address_space(3))) uint32_t*)(lp), 16, 0, 0)
#define BAR()  do { __builtin_amdgcn_s_barrier(); asm volatile("" ::: "memory"); } while (0)
#define WVM6() asm volatile("s_waitcnt vmcnt(6)" ::: "memory")
#define WVM0() asm volatile("s_waitcnt vmcnt(0)" ::: "memory")

// C[m, n] = A[m, :] @ W[:, n] over this chunk's nc columns.
// A: bf16 [rows, lda] (pre-offset). Bp: packets [K/8][nc][8] bf16.
// MODE 0: C bf16 = result. MODE 1: C bf16 = silu(C_old) * result (SwiGLU).
// MODE 2: C fp32 = result (final output).
//
// 8 phases per iteration (2 K-steps c0=2i [buffer X], c1=2i+1 [buffer Y]).
// Per wave (wm in {0,1} x wn in {0..3}): output 128x64, split into
// quadrants (rh in {0,1} x ch in {0,1}); phase = one quadrant x K=64.
//   ph1: rdA(X,rh0)+rdB(X,ch0)->bA | stage Y.A13(c1)   | MM(0,0,bA)
//   ph2: rdB(X,ch1)->bB           | stage X'.A02(s2)   | MM(0,1,bB)
//   ph3: rdA(X,rh1)               | stage X'.Bk0(s2)   | MM(1,0,bA)
//   ph4: --                       | stage X'.Bk1(s2)   | MM(1,1,bB) WVM6
//   ph5-8: same on Y / stages X'.A13(s2), Y'.A02/Bk0/Bk1(s3)
// Every stage lands 5-7 phases before first read; vmcnt(6) at ph4/ph8
// guards all consumptions (per-wave ledger verified; see notes).
template <int MODE>
__launch_bounds__(512, 2)
__global__ void gemm_bt_kernel(const ushort* __restrict__ A,
                               const ushort* __restrict__ Bp,
                               void* __restrict__ Cv,
                               int K, int nc, int lda, int ldc) {
  __shared__ ushort sA0[BM * BK];            // even K-steps, 32 KB
  __shared__ ushort sB0[(BK / 8) * BN * 8];  // even K-steps, 32 KB
  __shared__ ushort sA1[BM * BK];            // odd K-steps, 32 KB
  __shared__ ushort sB1[(BK / 8) * BN * 8];  // odd K-steps, 32 KB

  const int tid = threadIdx.x;
  const int w = tid >> 6;
  const int lane = tid & 63;
  const int l16 = lane & 15;
  const int quad = lane >> 4;
  const int wm = w >> 2;            // 0..1 (M)
  const int wn = w & 3;             // 0..3 (N)
  const int swz = l16 & 7;          // A-tile XOR swizzle key (row & 7)

  // Bijective XCD-aware block swizzle (m204 form).
  const int gx = gridDim.x;
  const int nwg = gx * (int)gridDim.y;
  const int orig = blockIdx.y * gx + blockIdx.x;
  const int q8 = nwg >> 3, r8 = nwg & 7;
  const int xcd = orig & 7, sidx = orig >> 3;
  const int wg = (xcd < r8 ? xcd * (q8 + 1) : r8 * (q8 + 1) + (xcd - r8) * q8) + sidx;
  const int m0 = (wg / gx) * BM;
  const int bn0 = (wg % gx) * BN;

  // Staging lane geometry (per-lane global src pre-swizzled; LDS dest linear).
  const int arow = tid >> 3;                      // 0..63 within 64-row slab
  const int apk8 = ((tid & 7) ^ (arow & 7)) * 8;  // swizzled source packet
  const int bpr = tid >> 8;                       // 0..1 packet-row in slab
  const int bcol = tid & 255;
  const ushort* aSrc = A + (size_t)(m0 + arow) * lda + apk8;
  const ushort* bSrc = Bp + ((size_t)bpr * nc + bn0 + bcol) * 8;

  f32x4 acc[2][2][4][2];  // [rh][ch][i][jj]
#pragma unroll
  for (int rh = 0; rh < 2; rh++)
#pragma unroll
    for (int ch = 0; ch < 2; ch++)
#pragma unroll
      for (int i = 0; i < 4; i++)
#pragma unroll
        for (int jj = 0; jj < 2; jj++)
          acc[rh][ch][i][jj] = (f32x4){0.f, 0.f, 0.f, 0.f};

  bf16x8 afr[4][2], bA[2][2], bB[2][2];

  const int NT = K / BK;    // even (4096/64=64, 11008/64=172)
  const int NI = NT >> 1;

  // Stage slab r of K-step s. A slab r = rows r*64..r*64+63 (8 KB each);
  // B slab r = packets r*2..r*2+1 (all 256 cols).
#define SA(r, s, buf) \
  GL_LDS(aSrc + (size_t)(r) * 64 * lda + (size_t)(s) * BK, (buf) + (r) * 4096 + w * 512)
#define SB(r, s, buf) \
  GL_LDS(bSrc + ((size_t)(s) * 8 + (r) * 2) * (size_t)nc * 8, (buf) + (r) * 4096 + w * 512)

  // Fragment reads (compiler emits ds_read_b128 + fine-grained lgkmcnt).
#define RD_A(sbuf, rh)                                                         \
  do {                                                                         \
    const ushort* _a = (sbuf) + ((size_t)(wm * 128 + (rh) * 64 + l16)) * 64;   \
    _Pragma("unroll") for (int i = 0; i < 4; i++) {                            \
      afr[i][0] = *(const bf16x8*)(_a + i * 1024 + ((quad ^ swz) * 8));        \
      afr[i][1] = *(const bf16x8*)(_a + i * 1024 + (((quad + 4) ^ swz) * 8));  \
    }                                                                          \
  } while (0)
#define RD_B(sbuf, ch, dst)                                                    \
  do {                                                                         \
    const int _c = wn * 64 + (ch) * 32 + l16;                                  \
    _Pragma("unroll") for (int jj = 0; jj < 2; jj++) {                         \
      dst[jj][0] = *(const bf16x8*)((sbuf) + ((quad * 256) + _c + jj * 16) * 8);       \
      dst[jj][1] = *(const bf16x8*)((sbuf) + (((quad + 4) * 256) + _c + jj * 16) * 8); \
    }                                                                          \
  } while (0)
#define MM(rh, ch, bset)                                                       \
  do {                                                                         \
    __builtin_amdgcn_s_setprio(1);                                             \
    _Pragma("unroll") for (int kk = 0; kk < 2; kk++)                           \
    _Pragma("unroll") for (int i = 0; i < 4; i++)                              \
    _Pragma("unroll") for (int jj = 0; jj < 2; jj++)                           \
      acc[rh][ch][i][jj] = __builtin_amdgcn_mfma_f32_16x16x32_bf16(            \
          afr[i][kk], bset[jj][kk], acc[rh][ch][i][jj], 0, 0, 0);              \
    __builtin_amdgcn_s_setprio(0);                                             \
  } while (0)

  // Prologue: step0 fully (first 8 loads), then step1 A02+Bk0+Bk1 (6 loads).
  SA(0, 0, sA0); SA(2, 0, sA0);
  SB(0, 0, sB0); SB(1, 0, sB0); SB(2, 0, sB0); SB(3, 0, sB0);
  SA(1, 0, sA0); SA(3, 0, sA0);
  SA(0, 1, sA1); SA(2, 1, sA1);
  SB(0, 1, sB1); SB(1, 1, sB1); SB(2, 1, sB1); SB(3, 1, sB1);
  WVM6();  // first 8 (= all of step 0) landed
  BAR();

#pragma unroll 1
  for (int it = 0; it < NI; ++it) {
    const int c1 = 2 * it + 1;
    const int s2 = (2 * it + 2 < NT) ? 2 * it + 2 : NT - 2;  // parity even
    const int s3 = (2 * it + 3 < NT) ? 2 * it + 3 : NT - 1;  // parity odd

    // ---- ph1 ----
    RD_A(sA0, 0); RD_B(sB0, 0, bA);
    SA(1, c1, sA1); SA(3, c1, sA1);        // Y.A13 (this iter, read ph7)
    BAR();
    MM(0, 0, bA);
    BAR();
    // ---- ph2 ----
    RD_B(sB0, 1, bB);
    SA(0, s2, sA0); SA(2, s2, sA0);        // X'.A02
    BAR();
    MM(0, 1, bB);
    BAR();
    // ---- ph3 ----
    RD_A(sA0, 1);
    SB(0, s2, sB0); SB(1, s2, sB0);        // X'.Bk0
    BAR();
    MM(1, 0, bA);
    BAR();
    // ---- ph4 ----
    SB(2, s2, sB0); SB(3, s2, sB0);        // X'.Bk1
    BAR();
    MM(1, 1, bB);
    WVM6();  // outstanding <= ph2,3,4 stages; Y fully landed for ph5-8
    BAR();
    // ---- ph5 ----
    RD_A(sA1, 0); RD_B(sB1, 0, bA);
    SA(1, s2, sA0); SA(3, s2, sA0);        // X'.A13
    BAR();
    MM(0, 0, bA);
    BAR();
    // ---- ph6 ----
    RD_B(sB1, 1, bB);
    SA(0, s3, sA1); SA(2, s3, sA1);        // Y'.A02
    BAR();
    MM(0, 1, bB);
    BAR();
    // ---- ph7 ----
    RD_A(sA1, 1);
    SB(0, s3, sB1); SB(1, s3, sB1);        // Y'.Bk0
    BAR();
    MM(1, 0, bA);
    BAR();
    // ---- ph8 ----
    SB(2, s3, sB1); SB(3, s3, sB1);        // Y'.Bk1
    BAR();
    MM(1, 1, bB);
    WVM6();  // outstanding <= ph6,7,8 stages; X' fully landed for next ph1-4
    BAR();
  }
  WVM0();  // drain trailing (re-)staged loads before epilogue

#undef SA
#undef SB
#undef RD_A
#undef RD_B
#undef MM

  // Epilogue. C/D frag layout: col = l16, row = quad*4 + r.
  // gm = m0 + wm*128 + rh*64 + i*16 + quad*4 + r; gn = bn0 + wn*64 + ch*32 + jj*16 + l16.
#pragma unroll
  for (int rh = 0; rh < 2; rh++) {
#pragma unroll
    for (int i = 0; i < 4; i++) {
#pragma unroll
      for (int r = 0; r < 4; r++) {
        const int gm = m0 + wm * 128 + rh * 64 + i * 16 + quad * 4 + r;
        if (MODE == 2) {
          float* crow = (float*)Cv + (size_t)gm * ldc + bn0 + wn * 64;
#pragma unroll
          for (int ch = 0; ch < 2; ch++)
#pragma unroll
            for (int jj = 0; jj < 2; jj++)
              crow[ch * 32 + jj * 16 + l16] = acc[rh][ch][i][jj][r];
        } else {
          ushort* crow = (ushort*)Cv + (size_t)gm * ldc + bn0 + wn * 64;
#pragma unroll
          for (int ch = 0; ch < 2; ch++)
#pragma unroll
            for (int jj = 0; jj < 2; jj++) {
              float v = acc[rh][ch][i][jj][r];
              const int cn = ch * 32 + jj * 16 + l16;
              if (MODE == 1) {
                const float gv = bf2f(crow[cn]);           // gate (bf16)
                v = (gv / (1.0f + __expf(-gv))) * v;       // silu(gate) * up
              }
              crow[cn] = f2bf_rne(v);
            }
        }
      }
    }
  }
}

extern "C" void kernel_launch(void* const* d_in, const int* in_sizes, int n_in,
                              void* d_out, int out_size, void* d_ws, size_t ws_size,
                              hipStream_t stream) {
  (void)n_in; (void)out_size;
  const float*   x   = (const float*)d_in[0];    // fp32 [4096, 4096]
  const int32_t* gq  = (const int32_t*)d_in[1];  // [512, 11008]
  const float*   gs  = (const float*)d_in[2];    // fp32 [32, 11008]
  const int32_t* gz  = (const int32_t*)d_in[3];  // [32, 1376]
  const int32_t* uq  = (const int32_t*)d_in[4];
  const float*   us  = (const float*)d_in[5];
  const int32_t* uz  = (const int32_t*)d_in[6];
  const int32_t* dq  = (const int32_t*)d_in[7];  // [1376, 4096]
  const float*   dsc = (const float*)d_in[8];    // fp32 [86, 4096]
  const int32_t* dz  = (const int32_t*)d_in[9];  // [86, 512]
  float* outp = (float*)d_out;                   // fp32 [4096, 4096]

  const int M = in_sizes[0] / HIDDEN;            // 4096

  // ---- ws-size-adaptive plan (all scratch strictly inside d_ws) ----
  const size_t W = ws_size;
  const size_t col12 = (size_t)HIDDEN * 2;   // 8192 B per dequant col (K=HIDDEN)
  const size_t col3  = (size_t)INTER * 2;    // 22016 B per dequant col (K=INTER)
  const size_t xb_bytes = (size_t)M * HIDDEN * 2;   // 33.5 MB
  int MC = 256;
  for (int cand = M; cand >= 256; cand >>= 1) {
    if (xb_bytes + (size_t)cand * INTER * 2 + col3 * 256 <= W) { MC = cand; break; }
  }
  ushort* xb = (ushort*)d_ws;                              // [M, HIDDEN] bf16
  ushort* gi = xb + (size_t)M * HIDDEN;                    // [MC, INTER] bf16
  ushort* wb = gi + (size_t)MC * INTER;                    // weight chunk
  const size_t used = xb_bytes + (size_t)MC * INTER * 2;
  const size_t wbuf = (W > used) ? W - used : 0;
  int NC12 = (int)(wbuf / col12); NC12 &= ~255;
  if (NC12 < 256) NC12 = 256;
  if (NC12 > INTER) NC12 = INTER;            // 11008 = 43*256
  int NC3 = (int)(wbuf / col3); NC3 &= ~255;
  if (NC3 < 256) NC3 = 256;
  if (NC3 > HIDDEN) NC3 = HIDDEN;

  // Convert x (fp32) -> xb (bf16) once.
  const int n4 = M * HIDDEN / 4;
  f32_to_bf16_kernel<<<(n4 + 255) / 256, 256, 0, stream>>>(x, xb, n4);

  for (int m0 = 0; m0 < M; m0 += MC) {
    const ushort* xm = xb + (size_t)m0 * HIDDEN;
    // Phase 1: gate = x @ Wg   (into gi, bf16)
    for (int n0 = 0; n0 < INTER; ) {
      int nc = INTER - n0; if (nc > NC12) nc = NC12;
      dequant_kernel<<<dim3(nc / 128, HIDDEN / 8), 128, 0, stream>>>(
          gq, gs, gz, wb, INTER, n0, nc);
      gemm_bt_kernel<0><<<dim3(nc / BN, MC / BM), 512, 0, stream>>>(
          xm, wb, gi + n0, HIDDEN, nc, HIDDEN, INTER);
      n0 += nc;
    }
    // Phase 2: inter = silu(gate) * (x @ Wu)   (in place over gi)
    for (int n0 = 0; n0 < INTER; ) {
      int nc = INTER - n0; if (nc > NC12) nc = NC12;
      dequant_kernel<<<dim3(nc / 128, HIDDEN / 8), 128, 0, stream>>>(
          uq, us, uz, wb, INTER, n0, nc);
      gemm_bt_kernel<1><<<dim3(nc / BN, MC / BM), 512, 0, stream>>>(
          xm, wb, gi + n0, HIDDEN, nc, HIDDEN, INTER);
      n0 += nc;
    }
    // Phase 3: out = inter @ Wd   (fp32 out)
    for (int n0 = 0; n0 < HIDDEN; ) {
      int nc = HIDDEN - n0; if (nc > NC3) nc = NC3;
      dequant_kernel<<<dim3(nc / 128, INTER / 8), 128, 0, stream>>>(
          dq, dsc, dz, wb, HIDDEN, n0, nc);
      gemm_bt_kernel<2><<<dim3(nc / BN, MC / BM), 512, 0, stream>>>(
          gi, wb, (void*)(outp + (size_t)m0 * HIDDEN + n0), INTER, nc, INTER, HIDDEN);
      n0 += nc;
    }
  }
}